// Round 17
// baseline (671.294 us; speedup 1.0000x reference)
//
#include <hip/hip_runtime.h>

#define N_NODES 50000
#define N_EDGES 800000
#define D_IN    64
#define D_HID   128
#define NBLK    ((N_NODES + 255) / 256)   // 196
#define NODEB   (N_NODES / 4)             // 12500 blocks x 4 waves

__device__ __forceinline__ float blo(unsigned r) { return __uint_as_float(r << 16); }
__device__ __forceinline__ float bhi(unsigned r) { return __uint_as_float(r & 0xFFFF0000u); }
__device__ __forceinline__ unsigned short f2bf(float f) {
    unsigned u = __float_as_uint(f);
    return (unsigned short)((u + 0x7FFFu + ((u >> 16) & 1u)) >> 16);
}

// ---- CSR build ----
__global__ void k_count(const int* __restrict__ rcv, int* __restrict__ deg) {
    int i = blockIdx.x * blockDim.x + threadIdx.x;
    if (i < N_EDGES) atomicAdd(&deg[rcv[i]], 1);
}

__global__ void k_blocksum(const int* __restrict__ deg, int* __restrict__ bsum) {
    int b = blockIdx.x, t = threadIdx.x;
    int i = b * 256 + t;
    int v = (i < N_NODES) ? deg[i] : 0;
#pragma unroll
    for (int o = 32; o >= 1; o >>= 1) v += __shfl_down(v, o);
    __shared__ int s[4];
    if ((t & 63) == 0) s[t >> 6] = v;
    __syncthreads();
    if (t == 0) bsum[b] = s[0] + s[1] + s[2] + s[3];
}

__global__ void k_scanb(const int* __restrict__ bsum, int* __restrict__ boff) {
    __shared__ int sh[256];
    int t = threadIdx.x;
    int v = (t < NBLK) ? bsum[t] : 0;
    sh[t] = v;
    __syncthreads();
    for (int d = 1; d < 256; d <<= 1) {
        int u = (t >= d) ? sh[t - d] : 0;
        __syncthreads();
        sh[t] += u;
        __syncthreads();
    }
    boff[t] = sh[t] - v;   // exclusive
}

__global__ void k_offsets(const int* __restrict__ deg, const int* __restrict__ boff,
                          int* __restrict__ off, int* __restrict__ cursor,
                          float* __restrict__ inv) {
    __shared__ int sh[256];
    int b = blockIdx.x, t = threadIdx.x, i = b * 256 + t;
    int d = (i < N_NODES) ? deg[i] : 0;
    sh[t] = d;
    __syncthreads();
    for (int o = 1; o < 256; o <<= 1) {
        int u = (t >= o) ? sh[t - o] : 0;
        __syncthreads();
        sh[t] += u;
        __syncthreads();
    }
    if (i < N_NODES) {
        int excl = boff[b] + sh[t] - d;
        off[i] = excl;
        cursor[i] = excl;
        inv[i] = d > 0 ? 1.0f / (float)d : 0.0f;
    }
    if (b == 0 && t == 0) off[N_NODES] = N_EDGES;
}

__global__ void k_fill(const int* __restrict__ snd, const int* __restrict__ rcv,
                       const float* __restrict__ w,
                       int* __restrict__ cursor,
                       int* __restrict__ e_snd, float* __restrict__ e_w) {
    int i = blockIdx.x * blockDim.x + threadIdx.x;
    if (i >= N_EDGES) return;
    int r = rcv[i];
    int p = atomicAdd(&cursor[r], 1);
    e_snd[p] = snd[i];
    e_w[p]   = w[i];
}

// ---- fp32 -> bf16 (RNE) pair-packed conversion ----
__global__ void k_tobf(const float* __restrict__ src, unsigned int* __restrict__ dst,
                       int npairs) {
    int i = blockIdx.x * blockDim.x + threadIdx.x;
    if (i >= npairs) return;
    float2 v = *(const float2*)(src + (size_t)i * 2);
    dst[i] = (unsigned)f2bf(v.x) | ((unsigned)f2bf(v.y) << 16);
}

// ---- fused layer: r14 base, row gathers as 1 dword/lane (full row = 1 instr) ----
// Lane l holds feats {2l,2l+1} (D=128) or half-wave split {2m,2m+1}, m=lane&31
// (D=64, alternate edges per half, combined by shfl_xor(32)). Descriptors are
// wave-uniform scalar loads (proven fast); NO shfl in address chain; unroll-2;
// NO non-temporal (r16: NT cost 28% via lost L2 allocation).
template<int DIN, bool RELU, bool DO_MLP>
__global__ __launch_bounds__(256) void k_layer(
        const float* __restrict__ h,
        const unsigned* __restrict__ hbw,       // bf16 rows, pair-packed uints
        const int* __restrict__ off,
        const int* __restrict__ e_snd,
        const float* __restrict__ e_w,
        const float* __restrict__ inv,
        const float* __restrict__ eps, int li,
        const float* __restrict__ W,
        const float* __restrict__ b,
        float* __restrict__ out) {
    constexpr int RW = DIN / 2;                 // uints per row
    int wave = threadIdx.x >> 6;
    int lane = threadIdx.x & 63;
    int n = blockIdx.x * 4 + wave;              // NODEB*4 == N_NODES

    int e0 = off[n], e1 = off[n + 1];
    float px = 0.0f, py = 0.0f;

    if constexpr (DIN == 128) {
        int e = e0;
        for (; e + 1 < e1; e += 2) {            // 2 row-loads in flight
            int s0 = e_snd[e], s1 = e_snd[e + 1];
            float w0 = e_w[e], w1 = e_w[e + 1];
            unsigned r0 = hbw[(size_t)s0 * RW + lane];
            unsigned r1 = hbw[(size_t)s1 * RW + lane];
            px += blo(r0) * w0 + blo(r1) * w1;
            py += bhi(r0) * w0 + bhi(r1) * w1;
        }
        if (e < e1) {
            int s0 = e_snd[e]; float w0 = e_w[e];
            unsigned r0 = hbw[(size_t)s0 * RW + lane];
            px += blo(r0) * w0;
            py += bhi(r0) * w0;
        }
    } else {                                    // DIN==64: half-wave per edge
        const int g = lane >> 5;
        const int m = lane & 31;
        int e = e0;
        for (; e + 3 < e1; e += 4) {            // 2 loads in flight per half
            int s0 = e_snd[e + g], s1 = e_snd[e + 2 + g];
            float w0 = e_w[e + g], w1 = e_w[e + 2 + g];
            unsigned r0 = hbw[(size_t)s0 * RW + m];
            unsigned r1 = hbw[(size_t)s1 * RW + m];
            px += blo(r0) * w0 + blo(r1) * w1;
            py += bhi(r0) * w0 + bhi(r1) * w1;
        }
        for (int ee = e + g; ee < e1; ee += 2) {
            int s0 = e_snd[ee]; float w0 = e_w[ee];
            unsigned r0 = hbw[(size_t)s0 * RW + m];
            px += blo(r0) * w0;
            py += bhi(r0) * w0;
        }
        px += __shfl_xor(px, 32);
        py += __shfl_xor(py, 32);
    }

    float se = 1.0f + eps[li];
    se = se > 0.0f ? se : 0.0f;                 // relu(1+eps)
    float id = inv[n];

    const int m2 = (DIN == 128) ? lane : (lane & 31);
    float2 hv = ((const float2*)(h + (size_t)n * DIN))[m2];
    float prex = hv.x * se + px * id;
    float prey = hv.y * se + py * id;

    if constexpr (!DO_MLP) {
        ((float2*)(out + (size_t)n * DIN))[m2] = make_float2(prex, prey);
        return;
    }

    // MLP: DIN -> 128; out cols {2l, 2l+1}; feat d lives in lane d>>1, elem d&1
    float2 acc = ((const float2*)b)[lane];
#pragma unroll
    for (int d = 0; d < DIN; ++d) {
        float pd = __shfl((d & 1) ? prey : prex, d >> 1);
        float2 wv = ((const float2*)(W + (size_t)d * 128))[lane];
        acc.x += pd * wv.x;
        acc.y += pd * wv.y;
    }
    if (RELU) {
        acc.x = acc.x > 0.0f ? acc.x : 0.0f;
        acc.y = acc.y > 0.0f ? acc.y : 0.0f;
    }
    ((float2*)(out + (size_t)n * 128))[lane] = acc;
}

// ---- standalone per-row MLP (layer-2 tail; layout-agnostic, r14-proven) ----
__global__ __launch_bounds__(256) void k_mlp(const float* __restrict__ pre,
                                             const float* __restrict__ W,
                                             const float* __restrict__ b,
                                             float* __restrict__ out) {
    int wave = threadIdx.x >> 6;
    int lane = threadIdx.x & 63;
    int n = blockIdx.x * 4 + wave;

    float2 p = ((const float2*)(pre + (size_t)n * 128))[lane];
    float2 acc = ((const float2*)b)[lane];
#pragma unroll
    for (int d = 0; d < 128; ++d) {
        float pd = __shfl((d & 1) ? p.y : p.x, d >> 1);
        float2 wv = ((const float2*)(W + (size_t)d * 128))[lane];
        acc.x += pd * wv.x;
        acc.y += pd * wv.y;
    }
    ((float2*)(out + (size_t)n * 128))[lane] = acc;
}

extern "C" void kernel_launch(void* const* d_in, const int* in_sizes, int n_in,
                              void* d_out, int out_size, void* d_ws, size_t ws_size,
                              hipStream_t stream) {
    const float* h0  = (const float*)d_in[0];
    const float* wts = (const float*)d_in[1];
    const int*   snd = (const int*)d_in[2];
    const int*   rcv = (const int*)d_in[3];
    const float* W0  = (const float*)d_in[4];
    const float* b0  = (const float*)d_in[5];
    const float* W1  = (const float*)d_in[6];
    const float* b1  = (const float*)d_in[7];
    const float* W2  = (const float*)d_in[8];
    const float* b2  = (const float*)d_in[9];
    const float* eps = (const float*)d_in[10];

    float* out0 = (float*)d_out;                  // node_embeddings
    float* out1 = out0 + (size_t)N_NODES * D_HID; // final h

    // ws layout (~20 MB), every array 256B-aligned (r14-proven).
    uintptr_t cur = (uintptr_t)d_ws;
    auto al = [&](size_t bytes) {
        cur = (cur + 255) & ~(uintptr_t)255;
        uintptr_t r = cur;
        cur += bytes;
        return r;
    };
    int*   deg    = (int*)  al((size_t)N_NODES * 4);
    int*   bsum   = (int*)  al(256 * 4);
    int*   boff   = (int*)  al(256 * 4);
    int*   off    = (int*)  al((size_t)(N_NODES + 1) * 4);
    int*   cursor = (int*)  al((size_t)N_NODES * 4);
    float* inv    = (float*)al((size_t)N_NODES * 4);
    int*   e_snd  = (int*)  al((size_t)N_EDGES * 4);
    float* e_w    = (float*)al((size_t)N_EDGES * 4);
    unsigned* hbw = (unsigned*)al((size_t)N_NODES * D_HID * 2);

    hipMemsetAsync(deg, 0, (size_t)N_NODES * sizeof(int), stream);
    k_count<<<(N_EDGES + 255) / 256, 256, 0, stream>>>(rcv, deg);
    k_blocksum<<<NBLK, 256, 0, stream>>>(deg, bsum);
    k_scanb<<<1, 256, 0, stream>>>(bsum, boff);
    k_offsets<<<NBLK, 256, 0, stream>>>(deg, boff, off, cursor, inv);
    k_fill<<<(N_EDGES + 255) / 256, 256, 0, stream>>>(snd, rcv, wts, cursor, e_snd, e_w);

    // L0: tobf(h0) ; gather(h0)+mlp0 -> out0 (= h1)
    k_tobf<<<(N_NODES * D_IN / 2 + 255) / 256, 256, 0, stream>>>(
        h0, hbw, N_NODES * D_IN / 2);
    k_layer<D_IN, true, true><<<NODEB, 256, 0, stream>>>(
        h0, hbw, off, e_snd, e_w, inv, eps, 0, W0, b0, out0);

    // L1: tobf(h1) ; gather(h1)+mlp1 -> out1 (= h2)
    k_tobf<<<(N_NODES * D_HID / 2 + 255) / 256, 256, 0, stream>>>(
        out0, hbw, N_NODES * D_HID / 2);
    k_layer<D_HID, true, true><<<NODEB, 256, 0, stream>>>(
        out0, hbw, off, e_snd, e_w, inv, eps, 1, W1, b1, out1);

    // L2a: tobf(h2) ; gather(h2) -> out0 (= node_embeddings)
    k_tobf<<<(N_NODES * D_HID / 2 + 255) / 256, 256, 0, stream>>>(
        out1, hbw, N_NODES * D_HID / 2);
    k_layer<D_HID, false, false><<<NODEB, 256, 0, stream>>>(
        out1, hbw, off, e_snd, e_w, inv, eps, 2, nullptr, nullptr, out0);

    // L2b: final MLP (no relu): out0 -> out1
    k_mlp<<<NODEB, 256, 0, stream>>>(out0, W2, b2, out1);
}

// Round 18
// 455.333 us; speedup vs baseline: 1.4743x; 1.4743x over previous
//
#include <hip/hip_runtime.h>

#define N_NODES 50000
#define N_EDGES 800000
#define D_IN    64
#define D_HID   128
#define NBLK    ((N_NODES + 255) / 256)   // 196

__device__ __forceinline__ float bf2f(unsigned short u) {
    return __uint_as_float(((unsigned)u) << 16);
}
__device__ __forceinline__ unsigned short f2bf(float f) {
    unsigned u = __float_as_uint(f);
    return (unsigned short)((u + 0x7FFFu + ((u >> 16) & 1u)) >> 16);
}

// ---- CSR build ----
__global__ void k_count(const int* __restrict__ rcv, int* __restrict__ deg) {
    int i = blockIdx.x * blockDim.x + threadIdx.x;
    if (i < N_EDGES) atomicAdd(&deg[rcv[i]], 1);
}

__global__ void k_blocksum(const int* __restrict__ deg, int* __restrict__ bsum) {
    int b = blockIdx.x, t = threadIdx.x;
    int i = b * 256 + t;
    int v = (i < N_NODES) ? deg[i] : 0;
#pragma unroll
    for (int o = 32; o >= 1; o >>= 1) v += __shfl_down(v, o);
    __shared__ int s[4];
    if ((t & 63) == 0) s[t >> 6] = v;
    __syncthreads();
    if (t == 0) bsum[b] = s[0] + s[1] + s[2] + s[3];
}

__global__ void k_scanb(const int* __restrict__ bsum, int* __restrict__ boff) {
    __shared__ int sh[256];
    int t = threadIdx.x;
    int v = (t < NBLK) ? bsum[t] : 0;
    sh[t] = v;
    __syncthreads();
    for (int d = 1; d < 256; d <<= 1) {
        int u = (t >= d) ? sh[t - d] : 0;
        __syncthreads();
        sh[t] += u;
        __syncthreads();
    }
    boff[t] = sh[t] - v;   // exclusive
}

__global__ void k_offsets(const int* __restrict__ deg, const int* __restrict__ boff,
                          int* __restrict__ off, int* __restrict__ cursor,
                          float* __restrict__ inv) {
    __shared__ int sh[256];
    int b = blockIdx.x, t = threadIdx.x, i = b * 256 + t;
    int d = (i < N_NODES) ? deg[i] : 0;
    sh[t] = d;
    __syncthreads();
    for (int o = 1; o < 256; o <<= 1) {
        int u = (t >= o) ? sh[t - o] : 0;
        __syncthreads();
        sh[t] += u;
        __syncthreads();
    }
    if (i < N_NODES) {
        int excl = boff[b] + sh[t] - d;
        off[i] = excl;
        cursor[i] = excl;
        inv[i] = d > 0 ? 1.0f / (float)d : 0.0f;
    }
    if (b == 0 && t == 0) off[N_NODES] = N_EDGES;
}

__global__ void k_fill(const int* __restrict__ snd, const int* __restrict__ rcv,
                       const float* __restrict__ w,
                       int* __restrict__ cursor,
                       int* __restrict__ e_snd, float* __restrict__ e_w) {
    int i = blockIdx.x * blockDim.x + threadIdx.x;
    if (i >= N_EDGES) return;
    int r = rcv[i];
    int p = atomicAdd(&cursor[r], 1);
    e_snd[p] = snd[i];
    e_w[p]   = w[i];
}

// ---- fp32 -> bf16 (RNE) pair-packed conversion ----
__global__ void k_tobf(const float* __restrict__ src, unsigned int* __restrict__ dst,
                       int npairs) {
    int i = blockIdx.x * blockDim.x + threadIdx.x;
    if (i >= npairs) return;
    float2 v = *(const float2*)(src + (size_t)i * 2);
    dst[i] = (unsigned)f2bf(v.x) | ((unsigned)f2bf(v.y) << 16);
}

// ---- fused layer: r14 load shape (1-line 128B ushort gathers), unroll-4 ----
// One wave per node; lane l holds feature(s) l (+64k). 4 edges unrolled ->
// 8 independent single-line requests in flight per wave (D=128). The load
// WIDTH stays 128B/instr (r17: 256B instrs lost 60% to completion-tail).
template<int DIN, int DOUT, bool RELU, bool DO_MLP>
__global__ __launch_bounds__(256) void k_layer(
        const float* __restrict__ h,
        const unsigned short* __restrict__ hb,
        const int* __restrict__ off,
        const int* __restrict__ e_snd,
        const float* __restrict__ e_w,
        const float* __restrict__ inv,
        const float* __restrict__ eps, int li,
        const float* __restrict__ W,
        const float* __restrict__ b,
        float* __restrict__ out) {
    constexpr int K = DIN / 64;
    int wave = threadIdx.x >> 6;
    int lane = threadIdx.x & 63;
    int n = blockIdx.x * (blockDim.x >> 6) + wave;
    if (n >= N_NODES) return;

    float pool[K];
#pragma unroll
    for (int k = 0; k < K; ++k) pool[k] = 0.0f;

    int e0 = off[n], e1 = off[n + 1];
    int e = e0;
    for (; e + 3 < e1; e += 4) {          // unroll-4: 4K 1-line loads in flight
        int s0 = e_snd[e],     s1 = e_snd[e + 1];
        int s2 = e_snd[e + 2], s3 = e_snd[e + 3];
        float w0 = e_w[e],     w1 = e_w[e + 1];
        float w2 = e_w[e + 2], w3 = e_w[e + 3];
        const unsigned short* p0 = hb + (size_t)s0 * DIN;
        const unsigned short* p1 = hb + (size_t)s1 * DIN;
        const unsigned short* p2 = hb + (size_t)s2 * DIN;
        const unsigned short* p3 = hb + (size_t)s3 * DIN;
        float a0[K], a1[K], a2[K], a3[K];
#pragma unroll
        for (int k = 0; k < K; ++k) {
            a0[k] = bf2f(p0[lane + 64 * k]);
            a1[k] = bf2f(p1[lane + 64 * k]);
            a2[k] = bf2f(p2[lane + 64 * k]);
            a3[k] = bf2f(p3[lane + 64 * k]);
        }
#pragma unroll
        for (int k = 0; k < K; ++k)
            pool[k] += a0[k] * w0 + a1[k] * w1 + a2[k] * w2 + a3[k] * w3;
    }
    for (; e + 1 < e1; e += 2) {          // unroll-2 tail
        int s0 = e_snd[e], s1 = e_snd[e + 1];
        float w0 = e_w[e], w1 = e_w[e + 1];
        const unsigned short* p0 = hb + (size_t)s0 * DIN;
        const unsigned short* p1 = hb + (size_t)s1 * DIN;
        float a0[K], a1[K];
#pragma unroll
        for (int k = 0; k < K; ++k) { a0[k] = bf2f(p0[lane + 64 * k]); a1[k] = bf2f(p1[lane + 64 * k]); }
#pragma unroll
        for (int k = 0; k < K; ++k) pool[k] += a0[k] * w0 + a1[k] * w1;
    }
    if (e < e1) {
        int s0 = e_snd[e]; float w0 = e_w[e];
        const unsigned short* p0 = hb + (size_t)s0 * DIN;
#pragma unroll
        for (int k = 0; k < K; ++k) pool[k] += bf2f(p0[lane + 64 * k]) * w0;
    }

    float se = 1.0f + eps[li];
    se = se > 0.0f ? se : 0.0f;           // relu(1+eps)
    float id = inv[n];
    const float* hr = h + (size_t)n * DIN;

    float pre[K];
#pragma unroll
    for (int k = 0; k < K; ++k) pre[k] = hr[lane + 64 * k] * se + pool[k] * id;

    if (!DO_MLP) {
        float* orow = out + (size_t)n * DIN;
#pragma unroll
        for (int k = 0; k < K; ++k) orow[lane + 64 * k] = pre[k];
        return;
    }

    float acc[DOUT / 64];
#pragma unroll
    for (int k = 0; k < DOUT / 64; ++k) acc[k] = b[lane + 64 * k];
#pragma unroll
    for (int d = 0; d < DIN; ++d) {
        float pd = __shfl(pre[d >> 6], d & 63);
#pragma unroll
        for (int k = 0; k < DOUT / 64; ++k)
            acc[k] += pd * W[d * DOUT + lane + 64 * k];
    }
    float* orow = out + (size_t)n * DOUT;
#pragma unroll
    for (int k = 0; k < DOUT / 64; ++k) {
        float v = acc[k];
        if (RELU) v = v > 0.0f ? v : 0.0f;
        orow[lane + 64 * k] = v;
    }
}

// ---- standalone per-row MLP (layer-2 tail; r7-proven) ----
template<int DIN, int DOUT, bool RELU>
__global__ __launch_bounds__(256) void k_mlp(const float* __restrict__ h,
                                             const float* __restrict__ W,
                                             const float* __restrict__ b,
                                             float* __restrict__ out) {
    int wave = threadIdx.x >> 6;
    int lane = threadIdx.x & 63;
    int n = blockIdx.x * (blockDim.x >> 6) + wave;
    if (n >= N_NODES) return;

    const float* hr = h + (size_t)n * DIN;
    float pre[DIN / 64];
#pragma unroll
    for (int k = 0; k < DIN / 64; ++k) pre[k] = hr[lane + 64 * k];

    float acc[DOUT / 64];
#pragma unroll
    for (int k = 0; k < DOUT / 64; ++k) acc[k] = b[lane + 64 * k];
#pragma unroll
    for (int d = 0; d < DIN; ++d) {
        float pd = __shfl(pre[d >> 6], d & 63);
#pragma unroll
        for (int k = 0; k < DOUT / 64; ++k)
            acc[k] += pd * W[d * DOUT + lane + 64 * k];
    }
    float* orow = out + (size_t)n * DOUT;
#pragma unroll
    for (int k = 0; k < DOUT / 64; ++k) {
        float v = acc[k];
        if (RELU) v = v > 0.0f ? v : 0.0f;
        orow[lane + 64 * k] = v;
    }
}

extern "C" void kernel_launch(void* const* d_in, const int* in_sizes, int n_in,
                              void* d_out, int out_size, void* d_ws, size_t ws_size,
                              hipStream_t stream) {
    const float* h0  = (const float*)d_in[0];
    const float* wts = (const float*)d_in[1];
    const int*   snd = (const int*)d_in[2];
    const int*   rcv = (const int*)d_in[3];
    const float* W0  = (const float*)d_in[4];
    const float* b0  = (const float*)d_in[5];
    const float* W1  = (const float*)d_in[6];
    const float* b1  = (const float*)d_in[7];
    const float* W2  = (const float*)d_in[8];
    const float* b2  = (const float*)d_in[9];
    const float* eps = (const float*)d_in[10];

    float* out0 = (float*)d_out;                  // node_embeddings
    float* out1 = out0 + (size_t)N_NODES * D_HID; // final h

    // ws layout (~20 MB), every array 256B-aligned (r14-proven).
    uintptr_t cur = (uintptr_t)d_ws;
    auto al = [&](size_t bytes) {
        cur = (cur + 255) & ~(uintptr_t)255;
        uintptr_t r = cur;
        cur += bytes;
        return r;
    };
    int*   deg    = (int*)  al((size_t)N_NODES * 4);
    int*   bsum   = (int*)  al(256 * 4);
    int*   boff   = (int*)  al(256 * 4);
    int*   off    = (int*)  al((size_t)(N_NODES + 1) * 4);
    int*   cursor = (int*)  al((size_t)N_NODES * 4);
    float* inv    = (float*)al((size_t)N_NODES * 4);
    int*   e_snd  = (int*)  al((size_t)N_EDGES * 4);
    float* e_w    = (float*)al((size_t)N_EDGES * 4);
    unsigned int* hb32 = (unsigned int*)al((size_t)N_NODES * D_HID * 2);
    unsigned short* hb = (unsigned short*)hb32;

    hipMemsetAsync(deg, 0, (size_t)N_NODES * sizeof(int), stream);
    k_count<<<(N_EDGES + 255) / 256, 256, 0, stream>>>(rcv, deg);
    k_blocksum<<<NBLK, 256, 0, stream>>>(deg, bsum);
    k_scanb<<<1, 256, 0, stream>>>(bsum, boff);
    k_offsets<<<NBLK, 256, 0, stream>>>(deg, boff, off, cursor, inv);
    k_fill<<<(N_EDGES + 255) / 256, 256, 0, stream>>>(snd, rcv, wts, cursor, e_snd, e_w);

    // L0: h0(64) -> out0(128), relu
    {
        int np = N_NODES * D_IN / 2;
        k_tobf<<<(np + 255) / 256, 256, 0, stream>>>(h0, hb32, np);
    }
    k_layer<D_IN, D_HID, true, true><<<N_NODES / 4, 256, 0, stream>>>(
        h0, hb, off, e_snd, e_w, inv, eps, 0, W0, b0, out0);

    // L1: out0 -> out1, relu
    {
        int np = N_NODES * D_HID / 2;
        k_tobf<<<(np + 255) / 256, 256, 0, stream>>>(out0, hb32, np);
    }
    k_layer<D_HID, D_HID, true, true><<<N_NODES / 4, 256, 0, stream>>>(
        out0, hb, off, e_snd, e_w, inv, eps, 1, W1, b1, out1);

    // L2a: gather+update only: out1 -> out0 (= node_embeddings)
    {
        int np = N_NODES * D_HID / 2;
        k_tobf<<<(np + 255) / 256, 256, 0, stream>>>(out1, hb32, np);
    }
    k_layer<D_HID, D_HID, false, false><<<N_NODES / 4, 256, 0, stream>>>(
        out1, hb, off, e_snd, e_w, inv, eps, 2, nullptr, nullptr, out0);

    // L2b: final MLP (no relu): out0 -> out1
    k_mlp<D_HID, D_HID, false><<<N_NODES / 4, 256, 0, stream>>>(out0, W2, b2, out1);
}

// Round 21
// 449.233 us; speedup vs baseline: 1.4943x; 1.0136x over previous
//
#include <hip/hip_runtime.h>

#define N_NODES 50000
#define N_EDGES 800000
#define D_IN    64
#define D_HID   128
#define NBLK    ((N_NODES + 255) / 256)   // 196

__device__ __forceinline__ float bf2f(unsigned short u) {
    return __uint_as_float(((unsigned)u) << 16);
}
__device__ __forceinline__ unsigned short f2bf(float f) {
    unsigned u = __float_as_uint(f);
    return (unsigned short)((u + 0x7FFFu + ((u >> 16) & 1u)) >> 16);
}

// ---- CSR build ----
__global__ void k_count(const int* __restrict__ rcv, int* __restrict__ deg) {
    int i = blockIdx.x * blockDim.x + threadIdx.x;
    if (i < N_EDGES) atomicAdd(&deg[rcv[i]], 1);
}

__global__ void k_blocksum(const int* __restrict__ deg, int* __restrict__ bsum) {
    int b = blockIdx.x, t = threadIdx.x;
    int i = b * 256 + t;
    int v = (i < N_NODES) ? deg[i] : 0;
#pragma unroll
    for (int o = 32; o >= 1; o >>= 1) v += __shfl_down(v, o);
    __shared__ int s[4];
    if ((t & 63) == 0) s[t >> 6] = v;
    __syncthreads();
    if (t == 0) bsum[b] = s[0] + s[1] + s[2] + s[3];
}

__global__ void k_scanb(const int* __restrict__ bsum, int* __restrict__ boff) {
    __shared__ int sh[256];
    int t = threadIdx.x;
    int v = (t < NBLK) ? bsum[t] : 0;
    sh[t] = v;
    __syncthreads();
    for (int d = 1; d < 256; d <<= 1) {
        int u = (t >= d) ? sh[t - d] : 0;
        __syncthreads();
        sh[t] += u;
        __syncthreads();
    }
    boff[t] = sh[t] - v;   // exclusive
}

__global__ void k_offsets(const int* __restrict__ deg, const int* __restrict__ boff,
                          int* __restrict__ off, int* __restrict__ cursor,
                          float* __restrict__ inv) {
    __shared__ int sh[256];
    int b = blockIdx.x, t = threadIdx.x, i = b * 256 + t;
    int d = (i < N_NODES) ? deg[i] : 0;
    sh[t] = d;
    __syncthreads();
    for (int o = 1; o < 256; o <<= 1) {
        int u = (t >= o) ? sh[t - o] : 0;
        __syncthreads();
        sh[t] += u;
        __syncthreads();
    }
    if (i < N_NODES) {
        int excl = boff[b] + sh[t] - d;
        off[i] = excl;
        cursor[i] = excl;
        inv[i] = d > 0 ? 1.0f / (float)d : 0.0f;
    }
    if (b == 0 && t == 0) off[N_NODES] = N_EDGES;
}

// packed (sender, weight-bits) CSR fill
__global__ void k_fill(const int* __restrict__ snd, const int* __restrict__ rcv,
                       const float* __restrict__ w,
                       int* __restrict__ cursor, int2* __restrict__ e_sw) {
    int i = blockIdx.x * blockDim.x + threadIdx.x;
    if (i >= N_EDGES) return;
    int r = rcv[i];
    int p = atomicAdd(&cursor[r], 1);
    e_sw[p] = make_int2(snd[i], __float_as_int(w[i]));
}

// ---- fp32 -> bf16 (RNE) pair-packed conversion ----
__global__ void k_tobf(const float* __restrict__ src, unsigned int* __restrict__ dst,
                       int npairs) {
    int i = blockIdx.x * blockDim.x + threadIdx.x;
    if (i >= npairs) return;
    float2 v = *(const float2*)(src + (size_t)i * 2);
    dst[i] = (unsigned)f2bf(v.x) | ((unsigned)f2bf(v.y) << 16);
}

// ---- fused layer: r18 gather + software-pipelined wave-uniform descriptors ----
// Descs packed as int2, read at WAVE-UNIFORM index (-> s_load_dwordx2).
// 2-stage pipeline: chunk c+1's descs are prefetched into registers BEFORE
// chunk c's row loads are consumed, hiding the s_load->v_load serial chain
// that is the hypothesized 108 cy/edge floor (invariant across r3..r18).
template<int DIN, int DOUT, bool RELU, bool DO_MLP>
__global__ __launch_bounds__(256) void k_layer(
        const float* __restrict__ h,
        const unsigned short* __restrict__ hb,
        const int* __restrict__ off,
        const int2* __restrict__ e_sw,
        const float* __restrict__ inv,
        const float* __restrict__ eps, int li,
        const float* __restrict__ W,
        const float* __restrict__ b,
        float* __restrict__ out) {
    constexpr int K = DIN / 64;
    int wave = threadIdx.x >> 6;
    int lane = threadIdx.x & 63;
    int n = blockIdx.x * (blockDim.x >> 6) + wave;
    if (n >= N_NODES) return;

    float pool[K];
#pragma unroll
    for (int k = 0; k < K; ++k) pool[k] = 0.0f;

    int e0 = off[n], e1 = off[n + 1];
    int nfull = (e1 - e0) >> 2;
    int e = e0;

    if (nfull > 0) {
        // prologue: prefetch chunk 0 descriptors
        int2 n0 = e_sw[e0 + 0], n1 = e_sw[e0 + 1];
        int2 n2 = e_sw[e0 + 2], n3 = e_sw[e0 + 3];
        for (int c = 0; c < nfull; ++c) {
            int2 c0 = n0, c1 = n1, c2 = n2, c3 = n3;
            int nb = e0 + (c + 1) * 4;
            if (c + 1 < nfull) {               // prefetch next chunk NOW —
                n0 = e_sw[nb + 0];             // its latency hides under the
                n1 = e_sw[nb + 1];             // row loads below
                n2 = e_sw[nb + 2];
                n3 = e_sw[nb + 3];
            }
            float w0 = __int_as_float(c0.y), w1 = __int_as_float(c1.y);
            float w2 = __int_as_float(c2.y), w3 = __int_as_float(c3.y);
            const unsigned short* p0 = hb + (size_t)c0.x * DIN;
            const unsigned short* p1 = hb + (size_t)c1.x * DIN;
            const unsigned short* p2 = hb + (size_t)c2.x * DIN;
            const unsigned short* p3 = hb + (size_t)c3.x * DIN;
            float a0[K], a1[K], a2[K], a3[K];
#pragma unroll
            for (int k = 0; k < K; ++k) {
                a0[k] = bf2f(p0[lane + 64 * k]);
                a1[k] = bf2f(p1[lane + 64 * k]);
                a2[k] = bf2f(p2[lane + 64 * k]);
                a3[k] = bf2f(p3[lane + 64 * k]);
            }
#pragma unroll
            for (int k = 0; k < K; ++k)
                pool[k] += a0[k] * w0 + a1[k] * w1 + a2[k] * w2 + a3[k] * w3;
        }
        e = e0 + nfull * 4;
    }
    for (; e < e1; ++e) {                      // <=3-edge tail
        int2 sw = e_sw[e];
        float w0 = __int_as_float(sw.y);
        const unsigned short* p0 = hb + (size_t)sw.x * DIN;
#pragma unroll
        for (int k = 0; k < K; ++k) pool[k] += bf2f(p0[lane + 64 * k]) * w0;
    }

    float se = 1.0f + eps[li];
    se = se > 0.0f ? se : 0.0f;           // relu(1+eps)
    float id = inv[n];
    const float* hr = h + (size_t)n * DIN;

    float pre[K];
#pragma unroll
    for (int k = 0; k < K; ++k) pre[k] = hr[lane + 64 * k] * se + pool[k] * id;

    if (!DO_MLP) {
        float* orow = out + (size_t)n * DIN;
#pragma unroll
        for (int k = 0; k < K; ++k) orow[lane + 64 * k] = pre[k];
        return;
    }

    float acc[DOUT / 64];
#pragma unroll
    for (int k = 0; k < DOUT / 64; ++k) acc[k] = b[lane + 64 * k];
#pragma unroll
    for (int d = 0; d < DIN; ++d) {
        float pd = __shfl(pre[d >> 6], d & 63);
#pragma unroll
        for (int k = 0; k < DOUT / 64; ++k)
            acc[k] += pd * W[d * DOUT + lane + 64 * k];
    }
    float* orow = out + (size_t)n * DOUT;
#pragma unroll
    for (int k = 0; k < DOUT / 64; ++k) {
        float v = acc[k];
        if (RELU) v = v > 0.0f ? v : 0.0f;
        orow[lane + 64 * k] = v;
    }
}

// ---- standalone per-row MLP (layer-2 tail; r7-proven) ----
template<int DIN, int DOUT, bool RELU>
__global__ __launch_bounds__(256) void k_mlp(const float* __restrict__ h,
                                             const float* __restrict__ W,
                                             const float* __restrict__ b,
                                             float* __restrict__ out) {
    int wave = threadIdx.x >> 6;
    int lane = threadIdx.x & 63;
    int n = blockIdx.x * (blockDim.x >> 6) + wave;
    if (n >= N_NODES) return;

    const float* hr = h + (size_t)n * DIN;
    float pre[DIN / 64];
#pragma unroll
    for (int k = 0; k < DIN / 64; ++k) pre[k] = hr[lane + 64 * k];

    float acc[DOUT / 64];
#pragma unroll
    for (int k = 0; k < DOUT / 64; ++k) acc[k] = b[lane + 64 * k];
#pragma unroll
    for (int d = 0; d < DIN; ++d) {
        float pd = __shfl(pre[d >> 6], d & 63);
#pragma unroll
        for (int k = 0; k < DOUT / 64; ++k)
            acc[k] += pd * W[d * DOUT + lane + 64 * k];
    }
    float* orow = out + (size_t)n * DOUT;
#pragma unroll
    for (int k = 0; k < DOUT / 64; ++k) {
        float v = acc[k];
        if (RELU) v = v > 0.0f ? v : 0.0f;
        orow[lane + 64 * k] = v;
    }
}

extern "C" void kernel_launch(void* const* d_in, const int* in_sizes, int n_in,
                              void* d_out, int out_size, void* d_ws, size_t ws_size,
                              hipStream_t stream) {
    const float* h0  = (const float*)d_in[0];
    const float* wts = (const float*)d_in[1];
    const int*   snd = (const int*)d_in[2];
    const int*   rcv = (const int*)d_in[3];
    const float* W0  = (const float*)d_in[4];
    const float* b0  = (const float*)d_in[5];
    const float* W1  = (const float*)d_in[6];
    const float* b1  = (const float*)d_in[7];
    const float* W2  = (const float*)d_in[8];
    const float* b2  = (const float*)d_in[9];
    const float* eps = (const float*)d_in[10];

    float* out0 = (float*)d_out;                  // node_embeddings
    float* out1 = out0 + (size_t)N_NODES * D_HID; // final h

    // ws layout (~20 MB), every array 256B-aligned (r14-proven).
    uintptr_t cur = (uintptr_t)d_ws;
    auto al = [&](size_t bytes) {
        cur = (cur + 255) & ~(uintptr_t)255;
        uintptr_t r = cur;
        cur += bytes;
        return r;
    };
    int*   deg    = (int*)  al((size_t)N_NODES * 4);
    int*   bsum   = (int*)  al(256 * 4);
    int*   boff   = (int*)  al(256 * 4);
    int*   off    = (int*)  al((size_t)(N_NODES + 1) * 4);
    int*   cursor = (int*)  al((size_t)N_NODES * 4);
    float* inv    = (float*)al((size_t)N_NODES * 4);
    int2*  e_sw   = (int2*) al((size_t)N_EDGES * 8);
    unsigned int* hb32 = (unsigned int*)al((size_t)N_NODES * D_HID * 2);
    unsigned short* hb = (unsigned short*)hb32;

    hipMemsetAsync(deg, 0, (size_t)N_NODES * sizeof(int), stream);
    k_count<<<(N_EDGES + 255) / 256, 256, 0, stream>>>(rcv, deg);
    k_blocksum<<<NBLK, 256, 0, stream>>>(deg, bsum);
    k_scanb<<<1, 256, 0, stream>>>(bsum, boff);
    k_offsets<<<NBLK, 256, 0, stream>>>(deg, boff, off, cursor, inv);
    k_fill<<<(N_EDGES + 255) / 256, 256, 0, stream>>>(snd, rcv, wts, cursor, e_sw);

    // L0: h0(64) -> out0(128), relu
    {
        int np = N_NODES * D_IN / 2;
        k_tobf<<<(np + 255) / 256, 256, 0, stream>>>(h0, hb32, np);
    }
    k_layer<D_IN, D_HID, true, true><<<N_NODES / 4, 256, 0, stream>>>(
        h0, hb, off, e_sw, inv, eps, 0, W0, b0, out0);

    // L1: out0 -> out1, relu
    {
        int np = N_NODES * D_HID / 2;
        k_tobf<<<(np + 255) / 256, 256, 0, stream>>>(out0, hb32, np);
    }
    k_layer<D_HID, D_HID, true, true><<<N_NODES / 4, 256, 0, stream>>>(
        out0, hb, off, e_sw, inv, eps, 1, W1, b1, out1);

    // L2a: gather+update only: out1 -> out0 (= node_embeddings)
    {
        int np = N_NODES * D_HID / 2;
        k_tobf<<<(np + 255) / 256, 256, 0, stream>>>(out1, hb32, np);
    }
    k_layer<D_HID, D_HID, false, false><<<N_NODES / 4, 256, 0, stream>>>(
        out1, hb, off, e_sw, inv, eps, 2, nullptr, nullptr, out0);

    // L2b: final MLP (no relu): out0 -> out1
    k_mlp<D_HID, D_HID, false><<<N_NODES / 4, 256, 0, stream>>>(out0, W2, b2, out1);
}